// Round 10
// baseline (1227.783 us; speedup 1.0000x reference)
//
#include <hip/hip_runtime.h>
#include <hip/hip_bf16.h>

typedef short    short8  __attribute__((ext_vector_type(8)));
typedef unsigned uint2v  __attribute__((ext_vector_type(2)));
typedef float    f32x4   __attribute__((ext_vector_type(4)));

#define B_TOT 4096
#define SEQ   256
#define NDOF  7
#define HDIM  256
#define ROWS  16
#define DTF   0.002f

// RNE float->bf16 (setup only)
static __device__ __forceinline__ unsigned short f2bf(float f) {
    union { float f; unsigned u; } u; u.f = f;
    unsigned x = u.u;
    unsigned r = (x + 0x7FFFu + ((x >> 16) & 1u)) >> 16;
    return (unsigned short)r;
}
static __device__ __forceinline__ unsigned cvt_pk_bf16(float lo, float hi) {
    unsigned r;
    asm("v_cvt_pk_bf16_f32 %0, %1, %2" : "=v"(r) : "v"(lo), "v"(hi));
    return r;
}
static __device__ __forceinline__ float silu(float p) {
    return p * __builtin_amdgcn_rcpf(1.0f + __expf(-p));
}

__global__ __launch_bounds__(512, 2)
void NeuralODE_kernel(const float* __restrict__ st0, const float* __restrict__ tq,
                      const float* __restrict__ W1,  const float* __restrict__ b1,
                      const float* __restrict__ W2,  const float* __restrict__ b2,
                      const float* __restrict__ W3,  const float* __restrict__ b3,
                      float* __restrict__ out)
{
    __shared__ __align__(16) short h1b[16 * 264];
    __shared__ __align__(16) short h2b[16 * 264];
    __shared__ __align__(16) short taub[SEQ * 16 * 8];   // [s][row][8] bf16, d=7 zero pad
    __shared__ __align__(16) float red[4][16][20];       // L3 partials, stride 20 (bank-clean)

    const int tid  = threadIdx.x;
    const int w    = tid >> 6;          // 8 waves
    const int lane = tid & 63;
    const int g    = lane >> 4;
    const int n    = lane & 15;
    const int b0   = blockIdx.x * ROWS;
    const int mb   = 32 * w;

    // ---------------- init: fill tau cache (R2 exact) --------------------------
    for (int i = tid; i < SEQ * ROWS; i += 512) taub[i * 8 + 7] = 0;
    for (int it = tid; it < ROWS * SEQ * NDOF; it += 512) {
        int row = it / (SEQ * NDOF);
        int off = it - row * (SEQ * NDOF);
        int s   = off / NDOF;
        int d   = off - s * NDOF;
        taub[s * 128 + row * 8 + d] = (short)f2bf(tq[(size_t)(b0 + row) * (SEQ * NDOF) + off]);
    }

    // ---------------- W1 frags, reg-build channel layout -----------------------
    // x: k0-3=q d0-3, k4-7=v d0-3, k8-10=q d4-6, k11=1(bias), k12-14=v d4-6,
    //    k15=0, k16-22=tau d0-6, k23-31=0
    short8 a1f[2];
#pragma unroll
    for (int t = 0; t < 2; ++t) {
        short8 fr;
#pragma unroll
        for (int j = 0; j < 8; ++j) {
            int k = 8 * g + j;
            int m = mb + 16 * t + n;
            float v;
            if (k < 4)        v = W1[k * HDIM + m];          // q d0-3
            else if (k < 8)   v = W1[(k + 3) * HDIM + m];    // v d0-3 (rows 7-10)
            else if (k < 11)  v = W1[(k - 4) * HDIM + m];    // q d4-6 (rows 4-6)
            else if (k == 11) v = b1[m];                     // bias
            else if (k < 15)  v = W1[(k - 1) * HDIM + m];    // v d4-6 (rows 11-13)
            else if (k == 15) v = 0.0f;
            else if (k < 23)  v = W1[(k - 2) * HDIM + m];    // tau d0-6 (rows 14-20)
            else              v = 0.0f;
            fr[j] = (short)f2bf(v);
        }
        a1f[t] = fr;
    }
    short8 a2f[2][8];
#pragma unroll
    for (int t = 0; t < 2; ++t)
#pragma unroll
        for (int ks = 0; ks < 8; ++ks) {
            short8 fr;
#pragma unroll
            for (int j = 0; j < 8; ++j) {
                int k = 32 * ks + 8 * g + j;
                fr[j] = (short)f2bf(W2[(size_t)k * HDIM + mb + 16 * t + n]);
            }
            a2f[t][ks] = fr;
        }
    // W3^T frags: wave w (w<4) owns k-slices {[32w,32w+32), [128+32w,128+32w+32)}
    // slice 0 == the wave's OWN h2 chunk -> pre-barrier readable
    short8 a3f[2] = {};
    if (w < 4) {
#pragma unroll
        for (int s = 0; s < 2; ++s) {
            short8 fr;
#pragma unroll
            for (int j = 0; j < 8; ++j) {
                int k = 128 * s + 32 * w + 8 * g + j;
                fr[j] = (n < NDOF) ? (short)f2bf(W3[k * NDOF + n]) : (short)0;
            }
            a3f[s] = fr;
        }
    }
    f32x4 b2v[2];
#pragma unroll
    for (int t = 0; t < 2; ++t) {
        int m = mb + 16 * t + 4 * g;
        f32x4 tv; tv[0] = b2[m]; tv[1] = b2[m + 1]; tv[2] = b2[m + 2]; tv[3] = b2[m + 3];
        b2v[t] = tv;
    }
    f32x4 b3v;
#pragma unroll
    for (int r = 0; r < 4; ++r) {
        int m = 4 * g + r;
        b3v[r] = (m < NDOF) ? b3[m] : 0.0f;
    }

    // ---------------- state (g<2 lanes own dofs d = 4g+r) ----------------------
    f32x4 q, v, a;
    const float* sp = st0 + (size_t)(b0 + n) * 14;
#pragma unroll
    for (int r = 0; r < 4; ++r) {
        int d = 4 * g + r;
        bool val = (g < 2) && (d < NDOF);
        q[r] = val ? sp[d] : 0.0f;
        v[r] = val ? sp[7 + d] : 0.0f;
        a[r] = 0.0f;
    }

    short8 tw = {};   // g2 lanes: tau bf16 words for the upcoming eval
    auto pf_tau = [&](int idx) {
        if (g == 2) tw = *(const short8*)&taub[idx * 128 + n * 8];
    };

    // register-only x-fragment build: g0/g1 pack own state, g2 = tau, g3 = 0
    auto build_xf = [&](f32x4 qq, f32x4 vv) -> short8 {
        float hq3 = (g == 1) ? 1.0f : qq[3];          // bias channel k11
        unsigned w0 = cvt_pk_bf16(qq[0], qq[1]);
        unsigned w1 = cvt_pk_bf16(qq[2], hq3);
        unsigned w2 = cvt_pk_bf16(vv[0], vv[1]);
        unsigned w3 = cvt_pk_bf16(vv[2], vv[3]);
        union { short8 s; unsigned u[4]; } tu, xu;
        tu.s = tw;
        bool t2 = (g == 2);
        xu.u[0] = t2 ? tu.u[0] : w0;
        xu.u[1] = t2 ? tu.u[1] : w1;
        xu.u[2] = t2 ? tu.u[2] : w2;
        xu.u[3] = t2 ? tu.u[3] : w3;
        return xu.s;                                   // g3: pk(0,0)=0 channels
    };

    short* h1w = &h1b[n * 264 + mb];
    short* h2w = &h2b[n * 264 + mb];
    const short* h1r = &h1b[n * 264 + 8 * g];

    auto accel = [&](short8 xf) -> f32x4 {
        const f32x4 cz = {0.0f, 0.0f, 0.0f, 0.0f};
        // ---- L1 ----
        f32x4 c1a = __builtin_amdgcn_mfma_f32_16x16x32_bf16(a1f[0], xf, cz, 0, 0, 0);
        f32x4 c1b = __builtin_amdgcn_mfma_f32_16x16x32_bf16(a1f[1], xf, cz, 0, 0, 0);
        {
            uint2v p;
            p[0] = cvt_pk_bf16(silu(c1a[0]), silu(c1a[1]));
            p[1] = cvt_pk_bf16(silu(c1a[2]), silu(c1a[3]));
            *(uint2v*)&h1w[4 * g] = p;
            p[0] = cvt_pk_bf16(silu(c1b[0]), silu(c1b[1]));
            p[1] = cvt_pk_bf16(silu(c1b[2]), silu(c1b[3]));
            *(uint2v*)&h1w[16 + 4 * g] = p;
        }
        // pre-read own h1 chunk (written by this wave -> no barrier needed)
        short8 b_own = *(const short8*)&h1r[32 * w];
        __syncthreads();   // B1

        // ---- L2: 4 chains depth 4, k-loop rotated so first MFMA uses b_own ----
        f32x4 c2a0 = b2v[0], c2b0 = b2v[1], c2a1 = cz, c2b1 = cz;
        c2a0 = __builtin_amdgcn_mfma_f32_16x16x32_bf16(a2f[0][w], b_own, c2a0, 0, 0, 0);
        c2b0 = __builtin_amdgcn_mfma_f32_16x16x32_bf16(a2f[1][w], b_own, c2b0, 0, 0, 0);
#pragma unroll
        for (int i = 1; i < 8; ++i) {
            int ks = (w + i) & 7;
            short8 bfr = *(const short8*)&h1r[32 * ks];
            if (i < 4) {
                c2a0 = __builtin_amdgcn_mfma_f32_16x16x32_bf16(a2f[0][ks], bfr, c2a0, 0, 0, 0);
                c2b0 = __builtin_amdgcn_mfma_f32_16x16x32_bf16(a2f[1][ks], bfr, c2b0, 0, 0, 0);
            } else {
                c2a1 = __builtin_amdgcn_mfma_f32_16x16x32_bf16(a2f[0][ks], bfr, c2a1, 0, 0, 0);
                c2b1 = __builtin_amdgcn_mfma_f32_16x16x32_bf16(a2f[1][ks], bfr, c2b1, 0, 0, 0);
            }
        }
        f32x4 c2a = c2a0 + c2a1, c2b = c2b0 + c2b1;
        {
            uint2v p;
            p[0] = cvt_pk_bf16(silu(c2a[0]), silu(c2a[1]));
            p[1] = cvt_pk_bf16(silu(c2a[2]), silu(c2a[3]));
            *(uint2v*)&h2w[4 * g] = p;
            p[0] = cvt_pk_bf16(silu(c2b[0]), silu(c2b[1]));
            p[1] = cvt_pk_bf16(silu(c2b[2]), silu(c2b[3]));
            *(uint2v*)&h2w[16 + 4 * g] = p;
        }
        // pre-read own h2 chunk (= L3 slice 0 for waves 0..3)
        short8 p_own = {};
        if (w < 4) p_own = *(const short8*)&h2b[n * 264 + 32 * w + 8 * g];
        __syncthreads();   // B2

        // ---- L3: waves 0..3, slice0 = own chunk (no post-barrier wait), slice1 read now
        if (w < 4) {
            f32x4 ci = (w == 0) ? b3v : cz;
            f32x4 c3 = __builtin_amdgcn_mfma_f32_16x16x32_bf16(a3f[0], p_own, ci, 0, 0, 0);
            short8 p1 = *(const short8*)&h2b[n * 264 + 128 + 32 * w + 8 * g];
            c3 = __builtin_amdgcn_mfma_f32_16x16x32_bf16(a3f[1], p1, c3, 0, 0, 0);
            if (g < 2) *(f32x4*)&red[w][n][4 * g] = c3;
        }
        __syncthreads();   // B3

        // ---- reduce 4 partials (g<2; C layout == state layout) ----
        f32x4 an = cz;
        if (g < 2) {
            const float* rb = &red[0][n][4 * g];
            f32x4 s0 = *(const f32x4*)(rb)       + *(const f32x4*)(rb + 320);
            f32x4 s1 = *(const f32x4*)(rb + 640) + *(const f32x4*)(rb + 960);
            an = s0 + s1;
        }
        return an;
    };

    __syncthreads();   // taub visible

    // ---------------- prologue: a0 = accel(x0), tau idx 0 ----------------------
    pf_tau(0);
    {
        short8 xf0 = build_xf(q, v);
        float tt = 1.0f * DTF;
        int ns = (int)floorf(tt / DTF);
        if (ns > SEQ - 1) ns = SEQ - 1;
        pf_tau(ns);
        a = accel(xf0);
    }

    // ---------------- 256 Verlet steps ------------------------------------------
    float* op = out + (size_t)(b0 + n) * SEQ * 14;

#pragma unroll 1
    for (int i = 0; i < SEQ; ++i) {
        f32x4 qn, vp;
#pragma unroll
        for (int r = 0; r < 4; ++r) {
            qn[r] = q[r] + v[r] * DTF + a[r] * (0.5f * DTF * DTF);
            vp[r] = v[r] + a[r] * DTF;
        }

        short8 xf = build_xf(qn, vp);

        // prefetch tau for next eval (R2 formula, one eval of slack)
        {
            float tt = (float)(i + 2) * DTF;
            int ns = (int)floorf(tt / DTF);
            if (ns > SEQ - 1) ns = SEQ - 1;
            pf_tau(ns);
        }

        f32x4 an = accel(xf);

#pragma unroll
        for (int r = 0; r < 4; ++r)
            v[r] = v[r] + (a[r] + an[r]) * (0.5f * DTF);
        q = qn;
        a = an;

        if (w == 0 && lane < 32) {
            float* o = op + (size_t)i * 14;
#pragma unroll
            for (int r = 0; r < 4; ++r) {
                int d = 4 * g + r;
                if (d < NDOF) { o[d] = qn[r]; o[7 + d] = v[r]; }
            }
        }
    }
}

extern "C" void kernel_launch(void* const* d_in, const int* in_sizes, int n_in,
                              void* d_out, int out_size, void* d_ws, size_t ws_size,
                              hipStream_t stream) {
    (void)in_sizes; (void)n_in; (void)d_ws; (void)ws_size; (void)out_size;
    const float* st0 = (const float*)d_in[0];
    const float* tq  = (const float*)d_in[1];
    const float* W1  = (const float*)d_in[2];
    const float* b1  = (const float*)d_in[3];
    const float* W2  = (const float*)d_in[4];
    const float* b2  = (const float*)d_in[5];
    const float* W3  = (const float*)d_in[6];
    const float* b3  = (const float*)d_in[7];

    NeuralODE_kernel<<<dim3(B_TOT / ROWS), dim3(512), 0, stream>>>(
        st0, tq, W1, b1, W2, b2, W3, b3, (float*)d_out);
}